// Round 14
// baseline (237.622 us; speedup 1.0000x reference)
//
#include <hip/hip_runtime.h>
#include <hip/hip_bf16.h>
#include <math.h>

#define B_  4
#define T_  2048
#define C_  1024
#define NH_ 16
#define HD_ 64

using bf16 = __hip_bfloat16;
typedef __attribute__((ext_vector_type(8))) short bf16x8;   // 8 bf16 (4 VGPRs)
typedef __attribute__((ext_vector_type(4))) short bf16x4;   // 4 bf16 (2 VGPRs)
typedef __attribute__((ext_vector_type(4))) float f32x4;

__device__ __forceinline__ bf16 f2b(float f){ return __float2bfloat16(f); }

// fast round-to-nearest-even fp32->bf16 (exact for all finite values; no NaN path)
__device__ __forceinline__ short f2bs(float f){
  union { float f; unsigned u; } x; x.f = f;
  x.u += 0x7FFFu + ((x.u >> 16) & 1u);
  return (short)(x.u >> 16);
}

// packed fp32x2 -> bf16x2 (v_cvt_pk_bf16_f32 on gfx950)
__device__ __forceinline__ bf16x4 pack_bf16x4(float a, float b, float c, float d){
  union { bf16x4 v; __hip_bfloat162 h[2]; } u;
  u.h[0] = __float22bfloat162_rn(make_float2(a, b));
  u.h[1] = __float22bfloat162_rn(make_float2(c, d));
  return u.v;
}

// raw v_exp_f32: exp2 with no ocml range-fixup wrapper.
__device__ __forceinline__ float fexp2(float x){
  float r; asm("v_exp_f32 %0, %1" : "=v"(r) : "v"(x)); return r;
}

__device__ __forceinline__ void async_load16(const bf16* g, bf16* l){
  __builtin_amdgcn_global_load_lds((const __attribute__((address_space(1))) unsigned int*)g,
                                   (__attribute__((address_space(3))) unsigned int*)l,
                                   16, 0, 0);
}

// 0.125 (1/sqrt(64)) * log2(e): softmax runs in exp2 domain
#define QSCALE 0.18033688011112042f

// ---------------- fused prep: x f32->bf16 (blocks 0..8191) + weight transposes ----------------
// ROUND 24: round-12 version (verified best).
__global__ __launch_bounds__(256) void k_prep(const float* __restrict__ x, bf16* __restrict__ xb, int n,
                                              const float* __restrict__ in0, bf16* __restrict__ out0,
                                              const float* __restrict__ in1, bf16* __restrict__ out1){
  __shared__ float t[32][33];
  int b = blockIdx.x;
  if (b < 8192){
    int i = (b * 256 + threadIdx.x) * 4;
    if (i < n){
      float4 f = *(const float4*)(x + i);
      ushort4 u;
      u.x = (unsigned short)f2bs(f.x);
      u.y = (unsigned short)f2bs(f.y);
      u.z = (unsigned short)f2bs(f.z);
      u.w = (unsigned short)f2bs(f.w);
      *(ushort4*)(xb + i) = u;
    }
    return;
  }
  b -= 8192;
  const float* in; bf16* out; int Cc, bx, by;
  if (b < 3072){ in = in0; out = out0; Cc = 3*C_; bx = (b % 96)*32; by = (b / 96)*32; }
  else { b -= 3072; in = in1; out = out1; Cc = C_; bx = (b & 31)*32; by = (b >> 5)*32; }
  const int R = C_;
  int lx = threadIdx.x & 31, ly = threadIdx.x >> 5;
  #pragma unroll
  for (int s = 0; s < 4; s++){
    int k = by + ly + s*8;
    t[ly + s*8][lx] = in[(size_t)k * Cc + bx + lx];
  }
  __syncthreads();
  #pragma unroll
  for (int s = 0; s < 4; s++){
    int n2 = bx + ly + s*8;
    out[(size_t)n2 * R + by + lx] = f2b(t[lx][ly + s*8]);
  }
}

// ------- GEMM0: 256x256 tile, 8 waves (2Mx4N, per-wave 128x64), pipelined tile body -------
// ROUND 24: round-13's 4-phase port stuck at MfmaUtil 31.7 — all 8 waves barrier-synced
// into the same phase: after each barrier every wave issues its ds_reads together (port
// storm, MFMA idle on lgkmcnt), then all MFMA together (port idle). Port (~375 cyc/CU/tile)
// and MFMA (~614 cyc/SIMD/tile) never overlap -> ~30% util, exactly as measured.
// Fix (m201's actual mechanism): within-wave software pipeline, ONE barrier per tile:
//   vmcnt(0)            // tile u's 8 loads staged EARLY in tile u-1's body (~4000 cyc ago)
//                       // -> landed; drain is ~free (unlike round-3's 200-cyc-old loads)
//   s_barrier + sched_barrier(0)   // certify k0+k1; WAR-protect buf d^1 (see below)
//   read set0 (bfv k0 + af-lo k0); stage ALL 8 of u+1 -> buf d^1; read set1 (af-hi k0)
//   MFMA c0 (set0)      // set1/set2 reads stream on the port underneath
//   read set2 (bfv k1 + af-lo k1)
//   MFMA c1 (set1 x bfv0)
//   read set3 (af-hi k1)
//   MFMA c2 (set2); MFMA c3 (set3 x bfv1)
// WAR safety: buf d^1 was read by tile u-1; every such ds_read feeds an MFMA issued before
// the tile-u barrier -> compiler's lgkmcnt forces completion before the wave passes it.
// Stage order no longer matters (wait is vmcnt(0)). Registers: 16 live b128 frags + acc
// ~230/wave -> __launch_bounds__(512,2) caps at 256 (2 waves/SIMD preserved).
// Swizzle + epilogue verbatim from round-13 (conflicts 0, WRITE ideal).
__global__ __launch_bounds__(512, 2) void k_gemm256(
    const bf16* __restrict__ A, const bf16* __restrict__ BT,
    const float* __restrict__ bias,
    bf16* __restrict__ qo, bf16* __restrict__ ko, bf16* __restrict__ vo,
    int M, int N, int K)
{
  extern __shared__ bf16 smem[];          // 128 KB: As[4][8192] then Bs[4][8192]
  bf16* As = smem;
  bf16* Bs = smem + 4*8192;

  const int tid  = threadIdx.x;
  const int wave = tid >> 6, lane = tid & 63;
  const int wm = wave >> 2, wn = wave & 3;      // 2M x 4N; per-wave 128 x 64
  const int quad = lane >> 4, l15 = lane & 15;
  const int bm = blockIdx.x * 256;
  const int bn = blockIdx.y * 256;

  // staging: per half-matrix (256x32) 1024 chunks of 16B; thread covers c = tid, tid+512
  const bf16* gA[2]; const bf16* gB[2]; int lofs[2];
  #pragma unroll
  for (int s = 0; s < 2; s++){
    const int c = tid + s*512;
    const int r = c >> 2, p = (c & 3) ^ ((r >> 1) & 3);
    gA[s] = A  + (size_t)(bm + r)*K + p*8;
    gB[s] = BT + (size_t)(bn + r)*K + p*8;
    lofs[s] = c*8;
  }
  const int fsw = (l15 >> 1) & 3;      // fragment-read chunk XOR

  f32x4 acc[8][4] = {};
  const int S = K >> 6;                // 16 tiles of BK=64

  // prologue: tile 0 (k0 -> sub-buf 0, k1 -> sub-buf 1)
  #pragma unroll
  for (int kh = 0; kh < 2; kh++){
    #pragma unroll
    for (int s = 0; s < 2; s++) async_load16(gA[s] + kh*32, As + kh*8192 + lofs[s]);
    #pragma unroll
    for (int s = 0; s < 2; s++) async_load16(gB[s] + kh*32, Bs + kh*8192 + lofs[s]);
  }

  for (int u = 0; u < S; u++){
    const int d  = u & 1;
    const int e2 = (d ^ 1) * 2;
    const bf16* a0 = As + (d*2+0)*8192;
    const bf16* a1 = As + (d*2+1)*8192;
    const bf16* b0 = Bs + (d*2+0)*8192;
    const bf16* b1 = Bs + (d*2+1)*8192;
    const bool pre = (u + 1 < S);
    const int off0 = (u + 1) * 64;

    asm volatile("s_waitcnt vmcnt(0)" ::: "memory");
    __builtin_amdgcn_s_barrier();
    __builtin_amdgcn_sched_barrier(0);

    bf16x8 bfv0[4], bfv1[4], afA[4], afB[4];

    // R0: bfv k0 + af-lo k0
    #pragma unroll
    for (int j = 0; j < 4; j++)
      bfv0[j] = *reinterpret_cast<const bf16x8*>(b0 + (wn*64 + j*16 + l15)*32 + ((quad ^ fsw) << 3));
    #pragma unroll
    for (int i = 0; i < 4; i++)
      afA[i]  = *reinterpret_cast<const bf16x8*>(a0 + (wm*128 + i*16 + l15)*32 + ((quad ^ fsw) << 3));

    // stage ALL of tile u+1 -> other dbuf (flies until top of tile u+1)
    if (pre){
      async_load16(gA[0] + off0,      As + e2*8192 + lofs[0]);
      async_load16(gA[1] + off0,      As + e2*8192 + lofs[1]);
      async_load16(gB[0] + off0,      Bs + e2*8192 + lofs[0]);
      async_load16(gB[1] + off0,      Bs + e2*8192 + lofs[1]);
      async_load16(gA[0] + off0 + 32, As + (e2+1)*8192 + lofs[0]);
      async_load16(gA[1] + off0 + 32, As + (e2+1)*8192 + lofs[1]);
      async_load16(gB[0] + off0 + 32, Bs + (e2+1)*8192 + lofs[0]);
      async_load16(gB[1] + off0 + 32, Bs + (e2+1)*8192 + lofs[1]);
    }

    // R1: af-hi k0 (streams under C0)
    #pragma unroll
    for (int i = 0; i < 4; i++)
      afB[i]  = *reinterpret_cast<const bf16x8*>(a0 + (wm*128 + 64 + i*16 + l15)*32 + ((quad ^ fsw) << 3));

    // C0: m-lo x k0
    __builtin_amdgcn_s_setprio(1);
    #pragma unroll
    for (int i = 0; i < 4; i++)
      #pragma unroll
      for (int j = 0; j < 4; j++)
        acc[i][j] = __builtin_amdgcn_mfma_f32_16x16x32_bf16(afA[i], bfv0[j], acc[i][j], 0, 0, 0);
    __builtin_amdgcn_s_setprio(0);

    // R2: bfv k1 + af-lo k1 (streams under C1)
    #pragma unroll
    for (int j = 0; j < 4; j++)
      bfv1[j] = *reinterpret_cast<const bf16x8*>(b1 + (wn*64 + j*16 + l15)*32 + ((quad ^ fsw) << 3));
    #pragma unroll
    for (int i = 0; i < 4; i++)
      afA[i]  = *reinterpret_cast<const bf16x8*>(a1 + (wm*128 + i*16 + l15)*32 + ((quad ^ fsw) << 3));

    // C1: m-hi x k0
    __builtin_amdgcn_s_setprio(1);
    #pragma unroll
    for (int i = 0; i < 4; i++)
      #pragma unroll
      for (int j = 0; j < 4; j++)
        acc[4+i][j] = __builtin_amdgcn_mfma_f32_16x16x32_bf16(afB[i], bfv0[j], acc[4+i][j], 0, 0, 0);
    __builtin_amdgcn_s_setprio(0);

    // R3: af-hi k1 (streams under C2)
    #pragma unroll
    for (int i = 0; i < 4; i++)
      afB[i]  = *reinterpret_cast<const bf16x8*>(a1 + (wm*128 + 64 + i*16 + l15)*32 + ((quad ^ fsw) << 3));

    // C2: m-lo x k1
    __builtin_amdgcn_s_setprio(1);
    #pragma unroll
    for (int i = 0; i < 4; i++)
      #pragma unroll
      for (int j = 0; j < 4; j++)
        acc[i][j] = __builtin_amdgcn_mfma_f32_16x16x32_bf16(afA[i], bfv1[j], acc[i][j], 0, 0, 0);

    // C3: m-hi x k1
    #pragma unroll
    for (int i = 0; i < 4; i++)
      #pragma unroll
      for (int j = 0; j < 4; j++)
        acc[4+i][j] = __builtin_amdgcn_mfma_f32_16x16x32_bf16(afB[i], bfv1[j], acc[4+i][j], 0, 0, 0);
    __builtin_amdgcn_s_setprio(0);
  }

  // epilogue: C/D layout row = quad*4 + reg, col = lane&15
  {
    const int sec = bn >> 10;
    const int bb2 = bm >> 11;
    const int tb  = (bm & (T_ - 1)) + wm*128 + quad*4;
    const int hn  = ((bn & 1023) >> 6) + wn;
    const size_t bhx = (size_t)(bb2 * NH_ + hn);
    if (sec == 2){
      #pragma unroll
      for (int j = 0; j < 4; j++){
        const int d2 = j*16 + l15;
        const float bj = bias[bn + wn*64 + j*16 + l15];
        bf16* vrow = vo + (bhx * HD_ + d2) * (size_t)T_;
        const int sw = (l15 & 7) * 8;          // kv-swizzle (d&7 == l15&7)
        #pragma unroll
        for (int i = 0; i < 8; i++){
          const int t = (tb + i*16) ^ sw;
          *reinterpret_cast<bf16x4*>(vrow + t) =
            pack_bf16x4(acc[i][j][0] + bj, acc[i][j][1] + bj,
                        acc[i][j][2] + bj, acc[i][j][3] + bj);
        }
      }
    } else {
      bf16* dst = (sec == 0) ? qo : ko;
      const float sc = (sec == 0) ? QSCALE : 1.0f;
      bf16* base = dst + bhx * T_ * HD_;
      float bj[4];
      #pragma unroll
      for (int j = 0; j < 4; j++) bj[j] = bias[bn + wn*64 + j*16 + l15];
      // row-completing order: j innermost -> full 128-B line dirty in consecutive stores
      #pragma unroll
      for (int i = 0; i < 8; i++){
        #pragma unroll
        for (int r = 0; r < 4; r++){
          const int t  = tb + i*16 + r;
          const int sw2 = (t & 7) * 8;
          bf16* prow = base + (size_t)t * HD_;
          #pragma unroll
          for (int j = 0; j < 4; j++){
            const int dq = (j*16 + l15) ^ sw2;   // d-swizzle
            short s = f2bs((acc[i][j][r] + bj[j]) * sc);
            prow[dq] = *(bf16*)&s;
          }
        }
      }
    }
  }
}

// ------- GEMM (proj): 128x128 tile, BK=64 two k-sub-stages, counted-vmcnt (round-8) -------
// ROUND 24: VERBATIM round-8 structure (control).
template<int MODE>
__global__ __launch_bounds__(256, 2) void k_gemm8(
    const bf16* __restrict__ A, const bf16* __restrict__ BT,
    const float* __restrict__ bias,
    bf16* __restrict__ qo, bf16* __restrict__ ko, bf16* __restrict__ vo,
    float* __restrict__ fout,
    int M, int N, int K)
{
  __shared__ bf16 As[2][2][128*32];
  __shared__ bf16 Bs[2][2][128*32];

  const int tid  = threadIdx.x;
  const int wave = tid >> 6, lane = tid & 63;
  const int wm = wave & 1, wn = wave >> 1;          // 2M x 2N wave grid
  const int quad = lane >> 4, l15 = lane & 15;
  const int bm = blockIdx.x * 128;
  const int bn = blockIdx.y * 128;

  const bf16* gA[2]; const bf16* gB[2]; int lofs[2];
  #pragma unroll
  for (int s = 0; s < 2; s++){
    const int c = tid + s*256;
    const int r = c >> 2, p = (c & 3) ^ ((r >> 1) & 3);
    gA[s] = A  + (size_t)(bm + r)*K + p*8;
    gB[s] = BT + (size_t)(bn + r)*K + p*8;
    lofs[s] = c*8;
  }
  const int fsw = (l15 >> 1) & 3;      // fragment-read chunk XOR

  f32x4 acc[4][4] = {};
  const int nT = K >> 6;

  #pragma unroll
  for (int kh = 0; kh < 2; kh++)
    #pragma unroll
    for (int s = 0; s < 2; s++){
      async_load16(gA[s] + kh*32, &As[0][kh][0] + lofs[s]);
      async_load16(gB[s] + kh*32, &Bs[0][kh][0] + lofs[s]);
    }

  for (int u = 0; u < nT; u++){
    const int d = u & 1;
    #pragma unroll
    for (int kh = 0; kh < 2; kh++){
      if (u + 1 < nT || kh == 0) asm volatile("s_waitcnt vmcnt(4)" ::: "memory");
      else                       asm volatile("s_waitcnt vmcnt(0)" ::: "memory");
      __builtin_amdgcn_s_barrier();
      __builtin_amdgcn_sched_barrier(0);

      const bf16* as = &As[d][kh][0];
      const bf16* bs = &Bs[d][kh][0];
      bf16x8 af[4], bfv[4];
      #pragma unroll
      for (int i = 0; i < 4; i++)
        af[i]  = *reinterpret_cast<const bf16x8*>(as + (wm*64 + i*16 + l15)*32 + ((quad ^ fsw) << 3));
      #pragma unroll
      for (int j = 0; j < 4; j++)
        bfv[j] = *reinterpret_cast<const bf16x8*>(bs + (wn*64 + j*16 + l15)*32 + ((quad ^ fsw) << 3));

      if (u + 1 < nT){
        const int ko2 = (u + 1)*64 + kh*32;
        #pragma unroll
        for (int s = 0; s < 2; s++){
          async_load16(gA[s] + ko2, &As[d^1][kh][0] + lofs[s]);
          async_load16(gB[s] + ko2, &Bs[d^1][kh][0] + lofs[s]);
        }
      }

      __builtin_amdgcn_s_setprio(1);
      #pragma unroll
      for (int i = 0; i < 4; i++)
        #pragma unroll
        for (int j = 0; j < 4; j++)
          acc[i][j] = __builtin_amdgcn_mfma_f32_16x16x32_bf16(af[i], bfv[j], acc[i][j], 0, 0, 0);
      __builtin_amdgcn_s_setprio(0);
    }
  }

  if (MODE == 0){
    const int sec = bn >> 10;
    const int bb2 = bm >> 11;
    const int tb  = (bm & (T_ - 1)) + wm*64 + quad*4;
    const int hn  = ((bn & 1023) >> 6) + wn;
    const size_t bhx = (size_t)(bb2 * NH_ + hn);
    if (sec == 2){
      #pragma unroll
      for (int j = 0; j < 4; j++){
        const int d2 = j*16 + l15;
        const float bj = bias[bn + wn*64 + j*16 + l15];
        bf16* vrow = vo + (bhx * HD_ + d2) * (size_t)T_;
        const int sw = (l15 & 7) * 8;
        #pragma unroll
        for (int i = 0; i < 4; i++){
          const int t = (tb + i*16) ^ sw;
          *reinterpret_cast<bf16x4*>(vrow + t) =
            pack_bf16x4(acc[i][j][0] + bj, acc[i][j][1] + bj,
                        acc[i][j][2] + bj, acc[i][j][3] + bj);
        }
      }
    } else {
      bf16* dst = (sec == 0) ? qo : ko;
      const float sc = (sec == 0) ? QSCALE : 1.0f;
      bf16* base = dst + bhx * T_ * HD_;
      float bj[4];
      #pragma unroll
      for (int j = 0; j < 4; j++) bj[j] = bias[bn + wn*64 + j*16 + l15];
      #pragma unroll
      for (int i = 0; i < 4; i++){
        #pragma unroll
        for (int r = 0; r < 4; r++){
          const int t  = tb + i*16 + r;
          const int sw2 = (t & 7) * 8;
          bf16* prow = base + (size_t)t * HD_;
          #pragma unroll
          for (int j = 0; j < 4; j++){
            const int dq = (j*16 + l15) ^ sw2;
            short s = f2bs((acc[i][j][r] + bj[j]) * sc);
            prow[dq] = *(bf16*)&s;
          }
        }
      }
    }
  } else {
    const int n0 = bn + wn*64 + l15;
    float bj[4];
    #pragma unroll
    for (int j = 0; j < 4; j++) bj[j] = bias[n0 + j*16];
    #pragma unroll
    for (int i = 0; i < 4; i++){
      #pragma unroll
      for (int r = 0; r < 4; r++){
        float* p0 = fout + (size_t)(bm + wm*64 + i*16 + quad*4 + r) * N + n0;
        #pragma unroll
        for (int j = 0; j < 4; j++)
          p0[j*16] = acc[i][j][r] + bj[j];
      }
    }
  }
}

// ---------------- flash attention: async dbuf K/V, Q in regs, 128-row q-tiles ----------------
// ROUND 24: round-12 version (verified best; last-tile peel). Control.
__global__ __launch_bounds__(256) void k_attn(
    const bf16* __restrict__ Q, const bf16* __restrict__ Kg,
    const bf16* __restrict__ Vt, bf16* __restrict__ Y)
{
  __shared__ bf16 Ks[2][64*64];   // [kv][d'] unpadded
  __shared__ bf16 Vs[2][64*64];   // [d][kv'] unpadded

  const int bh = blockIdx.x;
  const int bb = bh >> 4, hh = bh & 15;
  const int qt = 15 - blockIdx.y;          // 128-row q-tile, reversed dispatch
  const int tid  = threadIdx.x;
  const int wave = tid >> 6, lane = tid & 63;
  const int quad = lane >> 4, l15 = lane & 15;
  const int swz  = (l15 & 7) * 8;        // fragment-read XOR (t&7 == l15&7 everywhere used)

  const size_t baseQK = (size_t)bh * T_ * HD_;
  const size_t baseV  = (size_t)bh * HD_ * T_;

  const int ca = wave, cb = wave + 4;
  const bf16* kg_a = Kg + baseQK + ca*512 + (size_t)lane*8;
  const bf16* kg_b = Kg + baseQK + cb*512 + (size_t)lane*8;
  const bf16* vg_a = Vt + baseV + (size_t)(ca*8 + (lane>>3)) * T_ + (lane&7)*8;
  const bf16* vg_b = Vt + baseV + (size_t)(cb*8 + (lane>>3)) * T_ + (lane&7)*8;
  bf16* kl_a0 = &Ks[0][0] + ca*512;  bf16* kl_b0 = &Ks[0][0] + cb*512;
  bf16* vl_a0 = &Vs[0][0] + ca*512;  bf16* vl_b0 = &Vs[0][0] + cb*512;

  bf16x4 ones_f;
  {
    short v = (l15 == 0) ? f2bs(1.0f) : (short)0;
    ones_f = (bf16x4){ v, v, v, v };
  }
  const f32x4 ZV = {0.0f, 0.0f, 0.0f, 0.0f};

  bf16x8 qf[2][2];
  #pragma unroll
  for (int s = 0; s < 2; s++){
    const int t = qt*128 + s*64 + wave*16 + l15;
    #pragma unroll
    for (int ks = 0; ks < 2; ks++){
      const int col = (ks*32 + quad*8) ^ swz;
      qf[s][ks] = *reinterpret_cast<const bf16x8*>(Q + baseQK + (size_t)t*HD_ + col);
    }
  }

  async_load16(kg_a, kl_a0);  async_load16(kg_b, kl_b0);
  async_load16(vg_a, vl_a0);  async_load16(vg_b, vl_b0);

  f32x4 o[2][5] = {};

  for (int j = 0; j <= 2*qt; j++){
    __syncthreads();

    {
      const int nb = ((j+1) & 1) * 4096;
      const size_t ko = (size_t)(j+1) * 64 * HD_;
      async_load16(kg_a + ko, kl_a0 + nb);  async_load16(kg_b + ko, kl_b0 + nb);
      async_load16(vg_a + (j+1)*64, vl_a0 + nb);
      async_load16(vg_b + (j+1)*64, vl_b0 + nb);
    }

    const bf16* ksb = &Ks[j & 1][0];
    const bf16* vsb = &Vs[j & 1][0];

    f32x4 st[2][4];
    __builtin_amdgcn_s_setprio(1);
    #pragma unroll
    for (int tk = 0; tk < 4; tk++){
      bf16x8 kf0 = *reinterpret_cast<const bf16x8*>(ksb + (tk*16 + l15)*64 + ((quad*8) ^ swz));
      bf16x8 kf1 = *reinterpret_cast<const bf16x8*>(ksb + (tk*16 + l15)*64 + ((32 + quad*8) ^ swz));
      st[0][tk] = __builtin_amdgcn_mfma_f32_16x16x32_bf16(kf0, qf[0][0], ZV, 0, 0, 0);
      st[1][tk] = __builtin_amdgcn_mfma_f32_16x16x32_bf16(kf0, qf[1][0], ZV, 0, 0, 0);
      st[0][tk] = __builtin_amdgcn_mfma_f32_16x16x32_bf16(kf1, qf[0][1], st[0][tk], 0, 0, 0);
      st[1][tk] = __builtin_amdgcn_mfma_f32_16x16x32_bf16(kf1, qf[1][1], st[1][tk], 0, 0, 0);
    }
    __builtin_amdgcn_s_setprio(0);

    bf16x4 pf[2][4];
    {
      const int qg = qt*128 + wave*16 + l15;
      const bool msk = (j == 2*qt);
      #pragma unroll
      for (int tk = 0; tk < 4; tk++){
        float e[4];
        #pragma unroll
        for (int r = 0; r < 4; r++){
          float sv = st[0][tk][r];
          if (msk){
            const int kvg = j*64 + tk*16 + quad*4 + r;
            if (kvg > qg) sv = -1e30f;
          }
          e[r] = fexp2(sv);
        }
        pf[0][tk] = pack_bf16x4(e[0], e[1], e[2], e[3]);
      }
    }
    #pragma unroll
    for (int tk = 0; tk < 4; tk++){
      float e[4];
      #pragma unroll
      for (int r = 0; r < 4; r++) e[r] = fexp2(st[1][tk][r]);
      pf[1][tk] = pack_bf16x4(e[0], e[1], e[2], e[3]);
    }

    __builtin_amdgcn_s_setprio(1);
    #pragma unroll
    for (int td = 0; td < 4; td++){
      #pragma unroll
      for (int tk = 0; tk < 4; tk++){
        bf16x4 vf = *reinterpret_cast<const bf16x4*>(vsb + (td*16 + l15)*64 + ((tk*16 + quad*4) ^ swz));
        o[0][td] = __builtin_amdgcn_mfma_f32_16x16x16bf16_1k(vf, pf[0][tk], o[0][td], 0, 0, 0);
        o[1][td] = __builtin_amdgcn_mfma_f32_16x16x16bf16_1k(vf, pf[1][tk], o[1][td], 0, 0, 0);
      }
    }
    #pragma unroll
    for (int tk = 0; tk < 4; tk++){
      o[0][4] = __builtin_amdgcn_mfma_f32_16x16x16bf16_1k(ones_f, pf[0][tk], o[0][4], 0, 0, 0);
      o[1][4] = __builtin_amdgcn_mfma_f32_16x16x16bf16_1k(ones_f, pf[1][tk], o[1][4], 0, 0, 0);
    }
    __builtin_amdgcn_s_setprio(0);
  }

  {
    const int j = 2*qt + 1;
    __syncthreads();

    const bf16* ksb = &Ks[j & 1][0];
    const bf16* vsb = &Vs[j & 1][0];

    f32x4 st1[4];
    __builtin_amdgcn_s_setprio(1);
    #pragma unroll
    for (int tk = 0; tk < 4; tk++){
      bf16x8 kf0 = *reinterpret_cast<const bf16x8*>(ksb + (tk*16 + l15)*64 + ((quad*8) ^ swz));
      bf16x8 kf1 = *reinterpret_cast<const bf16x8*>(ksb + (tk*16 + l15)*64 + ((32 + quad*8) ^ swz));
      st1[tk] = __builtin_amdgcn_mfma_f32_16x16x32_bf16(kf0, qf[1][0], ZV, 0, 0, 0);
      st1[tk] = __builtin_amdgcn_mfma_f32_16x16x32_bf16(kf1, qf[1][1], st1[tk], 0, 0, 0);
    }
    __builtin_amdgcn_s_setprio(0);

    bf16x4 pf1[4];
    {
      const int qg = qt*128 + 64 + wave*16 + l15;
      #pragma unroll
      for (int tk = 0; tk < 4; tk++){
        float e[4];
        #pragma unroll
        for (int r = 0; r < 4; r++){
          float sv = st1[tk][r];
          const int kvg = j*64 + tk*16 + quad*4 + r;
          if (kvg > qg) sv = -1e30f;
          e[r] = fexp2(sv);
        }
        pf1[tk] = pack_bf16x4(e[0], e[1], e[2], e[3]);
      }
    }

    __builtin_amdgcn_s_setprio(1);
    #pragma unroll
    for (int td = 0; td < 4; td++){
      #pragma unroll
      for (int tk = 0; tk < 4; tk++){
        bf16x4 vf = *reinterpret_cast<const bf16x4*>(vsb + (td*16 + l15)*64 + ((tk*16 + quad*4) ^ swz));
        o[1][td] = __builtin_amdgcn_mfma_f32_16x16x16bf16_1k(vf, pf1[tk], o[1][td], 0, 0, 0);
      }
    }
    #pragma unroll
    for (int tk = 0; tk < 4; tk++)
      o[1][4] = __builtin_amdgcn_mfma_f32_16x16x16bf16_1k(ones_f, pf1[tk], o[1][4], 0, 0, 0);
    __builtin_amdgcn_s_setprio(0);
  }

  #pragma unroll
  for (int s = 0; s < 2; s++){
    const float l = __shfl(o[s][4][0], l15, 64);
    const float inv = 1.0f / l;
    const int t = qt*128 + s*64 + wave*16 + l15;
    bf16* yrow = Y + ((size_t)(bb * T_ + t)) * C_ + hh * HD_;
    #pragma unroll
    for (int td = 0; td < 4; td++){
      *reinterpret_cast<bf16x4*>(yrow + td*16 + quad*4) =
        pack_bf16x4(o[s][td][0] * inv, o[s][td][1] * inv,
                    o[s][td][2] * inv, o[s][td][3] * inv);
    }
  }
}

// ---------------- launcher ----------------

extern "C" void kernel_launch(void* const* d_in, const int* in_sizes, int n_in,
                              void* d_out, int out_size, void* d_ws, size_t ws_size,
                              hipStream_t stream) {
  const float* x     = (const float*)d_in[0];
  const float* Wqkv  = (const float*)d_in[1];
  const float* bqkv  = (const float*)d_in[2];
  const float* Wproj = (const float*)d_in[3];
  const float* bproj = (const float*)d_in[4];
  float* out = (float*)d_out;

  const size_t M = (size_t)B_ * T_;
  char* w = (char*)d_ws;
  bf16* xb     = (bf16*)w;  w += M * C_ * 2;
  bf16* WqkvT  = (bf16*)w;  w += (size_t)3 * C_ * C_ * 2;
  bf16* WprojT = (bf16*)w;  w += (size_t)C_ * C_ * 2;
  bf16* Qb     = (bf16*)w;  w += M * C_ * 2;
  bf16* Kb     = (bf16*)w;  w += M * C_ * 2;
  bf16* Vtb    = (bf16*)w;  w += M * C_ * 2;
  bf16* Yb     = (bf16*)w;  w += M * C_ * 2;

  // one-time opt-in for 128 KB dynamic LDS on k_gemm256 (host-side, not a stream op)
  static bool attr_done = false;
  if (!attr_done){
    hipFuncSetAttribute(reinterpret_cast<const void*>(k_gemm256),
                        hipFuncAttributeMaxDynamicSharedMemorySize, 131072);
    attr_done = true;
  }

  {
    int n = (int)(M * C_);
    k_prep<<<dim3(12288), dim3(256), 0, stream>>>(x, xb, n, Wqkv, WqkvT, Wproj, WprojT);
  }
  k_gemm256<<<dim3(M/256, (3*C_)/256), dim3(512), 131072, stream>>>(
      xb, WqkvT, bqkv, Qb, Kb, Vtb, (int)M, 3*C_, C_);
  k_attn<<<dim3(64, 16), dim3(256), 0, stream>>>(Qb, Kb, Vtb, Yb);
  k_gemm8<1><<<dim3(M/128, C_/128), dim3(256), 0, stream>>>(
      Yb, WprojT, bproj, nullptr, nullptr, nullptr, out, (int)M, C_, C_);
}

// Round 15
// 229.571 us; speedup vs baseline: 1.0351x; 1.0351x over previous
//
#include <hip/hip_runtime.h>
#include <hip/hip_bf16.h>
#include <math.h>

#define B_  4
#define T_  2048
#define C_  1024
#define NH_ 16
#define HD_ 64

using bf16 = __hip_bfloat16;
typedef __attribute__((ext_vector_type(8))) short bf16x8;   // 8 bf16 (4 VGPRs)
typedef __attribute__((ext_vector_type(4))) short bf16x4;   // 4 bf16 (2 VGPRs)
typedef __attribute__((ext_vector_type(4))) float f32x4;

__device__ __forceinline__ bf16 f2b(float f){ return __float2bfloat16(f); }

// fast round-to-nearest-even fp32->bf16 (exact for all finite values; no NaN path)
__device__ __forceinline__ short f2bs(float f){
  union { float f; unsigned u; } x; x.f = f;
  x.u += 0x7FFFu + ((x.u >> 16) & 1u);
  return (short)(x.u >> 16);
}

// packed fp32x2 -> bf16x2 (v_cvt_pk_bf16_f32 on gfx950)
__device__ __forceinline__ bf16x4 pack_bf16x4(float a, float b, float c, float d){
  union { bf16x4 v; __hip_bfloat162 h[2]; } u;
  u.h[0] = __float22bfloat162_rn(make_float2(a, b));
  u.h[1] = __float22bfloat162_rn(make_float2(c, d));
  return u.v;
}

// raw v_exp_f32: exp2 with no ocml range-fixup wrapper.
__device__ __forceinline__ float fexp2(float x){
  float r; asm("v_exp_f32 %0, %1" : "=v"(r) : "v"(x)); return r;
}

__device__ __forceinline__ void async_load16(const bf16* g, bf16* l){
  __builtin_amdgcn_global_load_lds((const __attribute__((address_space(1))) unsigned int*)g,
                                   (__attribute__((address_space(3))) unsigned int*)l,
                                   16, 0, 0);
}

// 0.125 (1/sqrt(64)) * log2(e): softmax runs in exp2 domain
#define QSCALE 0.18033688011112042f

// ---------------- fused prep: x f32->bf16 (blocks 0..8191) + weight transposes ----------------
// ROUND 25 (FINAL): round-12 version (verified best).
__global__ __launch_bounds__(256) void k_prep(const float* __restrict__ x, bf16* __restrict__ xb, int n,
                                              const float* __restrict__ in0, bf16* __restrict__ out0,
                                              const float* __restrict__ in1, bf16* __restrict__ out1){
  __shared__ float t[32][33];
  int b = blockIdx.x;
  if (b < 8192){
    int i = (b * 256 + threadIdx.x) * 4;
    if (i < n){
      float4 f = *(const float4*)(x + i);
      ushort4 u;
      u.x = (unsigned short)f2bs(f.x);
      u.y = (unsigned short)f2bs(f.y);
      u.z = (unsigned short)f2bs(f.z);
      u.w = (unsigned short)f2bs(f.w);
      *(ushort4*)(xb + i) = u;
    }
    return;
  }
  b -= 8192;
  const float* in; bf16* out; int Cc, bx, by;
  if (b < 3072){ in = in0; out = out0; Cc = 3*C_; bx = (b % 96)*32; by = (b / 96)*32; }
  else { b -= 3072; in = in1; out = out1; Cc = C_; bx = (b & 31)*32; by = (b >> 5)*32; }
  const int R = C_;
  int lx = threadIdx.x & 31, ly = threadIdx.x >> 5;
  #pragma unroll
  for (int s = 0; s < 4; s++){
    int k = by + ly + s*8;
    t[ly + s*8][lx] = in[(size_t)k * Cc + bx + lx];
  }
  __syncthreads();
  #pragma unroll
  for (int s = 0; s < 4; s++){
    int n2 = bx + ly + s*8;
    out[(size_t)n2 * R + by + lx] = f2b(t[lx][ly + s*8]);
  }
}

// ------- GEMM0: 256x256 tile, 8 waves (2Mx4N, per-wave 128x64), BK=64 in 4 phases -------
// ROUND 25 (FINAL): VERBATIM round-13 — best measured (234.64 total, gemm0 65.9 us).
// Counted vmcnt never 0 in steady state; phase-split MFMA clusters between barriers;
// setprio around MFMA; 128 KB dynamic LDS; 1 block/CU. Round-14's single-barrier
// pipelined variant REGRESSED (71 us, MfmaUtil 27.8) — do not reapply.
// Ledger: stage order per tile = Ak0,Bk0,Ak1,Bk1 (2 loads each, 1 half-matrix per phase
// for tile u+1). ph0: vmcnt(4) retires Ak0(u),Bk0(u). ph2: vmcnt(4) retires Ak1(u),Bk1(u)
// (last tile: vmcnt(0)). Cert: vmcnt -> s_barrier -> ds_read. WAR: stages into buf e land
// after ph0 barrier (all waves' tile u-1 reads already fed MFMAs).
__global__ __launch_bounds__(512) void k_gemm256(
    const bf16* __restrict__ A, const bf16* __restrict__ BT,
    const float* __restrict__ bias,
    bf16* __restrict__ qo, bf16* __restrict__ ko, bf16* __restrict__ vo,
    int M, int N, int K)
{
  extern __shared__ bf16 smem[];          // 128 KB: As[4][8192] then Bs[4][8192]
  bf16* As = smem;
  bf16* Bs = smem + 4*8192;

  const int tid  = threadIdx.x;
  const int wave = tid >> 6, lane = tid & 63;
  const int wm = wave >> 2, wn = wave & 3;      // 2M x 4N; per-wave 128 x 64
  const int quad = lane >> 4, l15 = lane & 15;
  const int bm = blockIdx.x * 256;
  const int bn = blockIdx.y * 256;

  // staging: per half-matrix (256x32) 1024 chunks of 16B; thread covers c = tid, tid+512
  const bf16* gA[2]; const bf16* gB[2]; int lofs[2];
  #pragma unroll
  for (int s = 0; s < 2; s++){
    const int c = tid + s*512;
    const int r = c >> 2, p = (c & 3) ^ ((r >> 1) & 3);
    gA[s] = A  + (size_t)(bm + r)*K + p*8;
    gB[s] = BT + (size_t)(bn + r)*K + p*8;
    lofs[s] = c*8;
  }
  const int fsw = (l15 >> 1) & 3;      // fragment-read chunk XOR

  f32x4 acc[8][4] = {};
  const int S = K >> 6;                // 16 tiles of BK=64

  // prologue: tile 0, order Ak0, Bk0, Ak1, Bk1 (FIFO positions for the counted waits)
  #pragma unroll
  for (int kh = 0; kh < 2; kh++){
    #pragma unroll
    for (int s = 0; s < 2; s++) async_load16(gA[s] + kh*32, As + kh*8192 + lofs[s]);
    #pragma unroll
    for (int s = 0; s < 2; s++) async_load16(gB[s] + kh*32, Bs + kh*8192 + lofs[s]);
  }

  for (int u = 0; u < S; u++){
    const int d  = u & 1;
    const int e2 = (d ^ 1) * 2;
    const bf16* a0 = As + (d*2+0)*8192;
    const bf16* a1 = As + (d*2+1)*8192;
    const bf16* b0 = Bs + (d*2+0)*8192;
    const bf16* b1 = Bs + (d*2+1)*8192;
    const bool pre = (u + 1 < S);
    const int off0 = (u + 1) * 64;

    bf16x8 bfv[4], af[4];

    // ---- ph0: certify k0(u); stage Ak0(u+1); compute m0..3 x k0 ----
    asm volatile("s_waitcnt vmcnt(4)" ::: "memory");
    __builtin_amdgcn_s_barrier();
    __builtin_amdgcn_sched_barrier(0);
    if (pre){
      async_load16(gA[0] + off0, As + e2*8192 + lofs[0]);
      async_load16(gA[1] + off0, As + e2*8192 + lofs[1]);
    }
    #pragma unroll
    for (int j = 0; j < 4; j++)
      bfv[j] = *reinterpret_cast<const bf16x8*>(b0 + (wn*64 + j*16 + l15)*32 + ((quad ^ fsw) << 3));
    #pragma unroll
    for (int i = 0; i < 4; i++)
      af[i]  = *reinterpret_cast<const bf16x8*>(a0 + (wm*128 + i*16 + l15)*32 + ((quad ^ fsw) << 3));
    __builtin_amdgcn_s_setprio(1);
    #pragma unroll
    for (int i = 0; i < 4; i++)
      #pragma unroll
      for (int j = 0; j < 4; j++)
        acc[i][j] = __builtin_amdgcn_mfma_f32_16x16x32_bf16(af[i], bfv[j], acc[i][j], 0, 0, 0);
    __builtin_amdgcn_s_setprio(0);

    // ---- ph1: stage Bk0(u+1); compute m4..7 x k0 ----
    if (pre){
      async_load16(gB[0] + off0, Bs + e2*8192 + lofs[0]);
      async_load16(gB[1] + off0, Bs + e2*8192 + lofs[1]);
    }
    #pragma unroll
    for (int i = 0; i < 4; i++)
      af[i]  = *reinterpret_cast<const bf16x8*>(a0 + (wm*128 + 64 + i*16 + l15)*32 + ((quad ^ fsw) << 3));
    __builtin_amdgcn_s_setprio(1);
    #pragma unroll
    for (int i = 0; i < 4; i++)
      #pragma unroll
      for (int j = 0; j < 4; j++)
        acc[4+i][j] = __builtin_amdgcn_mfma_f32_16x16x32_bf16(af[i], bfv[j], acc[4+i][j], 0, 0, 0);
    __builtin_amdgcn_s_setprio(0);

    // ---- ph2: certify k1(u); stage Ak1(u+1); compute m0..3 x k1 ----
    if (pre) asm volatile("s_waitcnt vmcnt(4)" ::: "memory");
    else     asm volatile("s_waitcnt vmcnt(0)" ::: "memory");
    __builtin_amdgcn_s_barrier();
    __builtin_amdgcn_sched_barrier(0);
    if (pre){
      async_load16(gA[0] + off0 + 32, As + (e2+1)*8192 + lofs[0]);
      async_load16(gA[1] + off0 + 32, As + (e2+1)*8192 + lofs[1]);
    }
    #pragma unroll
    for (int j = 0; j < 4; j++)
      bfv[j] = *reinterpret_cast<const bf16x8*>(b1 + (wn*64 + j*16 + l15)*32 + ((quad ^ fsw) << 3));
    #pragma unroll
    for (int i = 0; i < 4; i++)
      af[i]  = *reinterpret_cast<const bf16x8*>(a1 + (wm*128 + i*16 + l15)*32 + ((quad ^ fsw) << 3));
    __builtin_amdgcn_s_setprio(1);
    #pragma unroll
    for (int i = 0; i < 4; i++)
      #pragma unroll
      for (int j = 0; j < 4; j++)
        acc[i][j] = __builtin_amdgcn_mfma_f32_16x16x32_bf16(af[i], bfv[j], acc[i][j], 0, 0, 0);
    __builtin_amdgcn_s_setprio(0);

    // ---- ph3: stage Bk1(u+1); compute m4..7 x k1 ----
    if (pre){
      async_load16(gB[0] + off0 + 32, Bs + (e2+1)*8192 + lofs[0]);
      async_load16(gB[1] + off0 + 32, Bs + (e2+1)*8192 + lofs[1]);
    }
    #pragma unroll
    for (int i = 0; i < 4; i++)
      af[i]  = *reinterpret_cast<const bf16x8*>(a1 + (wm*128 + 64 + i*16 + l15)*32 + ((quad ^ fsw) << 3));
    __builtin_amdgcn_s_setprio(1);
    #pragma unroll
    for (int i = 0; i < 4; i++)
      #pragma unroll
      for (int j = 0; j < 4; j++)
        acc[4+i][j] = __builtin_amdgcn_mfma_f32_16x16x32_bf16(af[i], bfv[j], acc[4+i][j], 0, 0, 0);
    __builtin_amdgcn_s_setprio(0);
  }

  // epilogue: C/D layout row = quad*4 + reg, col = lane&15 (i<8, wm*128)
  {
    const int sec = bn >> 10;
    const int bb2 = bm >> 11;
    const int tb  = (bm & (T_ - 1)) + wm*128 + quad*4;
    const int hn  = ((bn & 1023) >> 6) + wn;
    const size_t bhx = (size_t)(bb2 * NH_ + hn);
    if (sec == 2){
      #pragma unroll
      for (int j = 0; j < 4; j++){
        const int d2 = j*16 + l15;
        const float bj = bias[bn + wn*64 + j*16 + l15];
        bf16* vrow = vo + (bhx * HD_ + d2) * (size_t)T_;
        const int sw = (l15 & 7) * 8;          // kv-swizzle (d&7 == l15&7)
        #pragma unroll
        for (int i = 0; i < 8; i++){
          const int t = (tb + i*16) ^ sw;
          *reinterpret_cast<bf16x4*>(vrow + t) =
            pack_bf16x4(acc[i][j][0] + bj, acc[i][j][1] + bj,
                        acc[i][j][2] + bj, acc[i][j][3] + bj);
        }
      }
    } else {
      bf16* dst = (sec == 0) ? qo : ko;
      const float sc = (sec == 0) ? QSCALE : 1.0f;
      bf16* base = dst + bhx * T_ * HD_;
      float bj[4];
      #pragma unroll
      for (int j = 0; j < 4; j++) bj[j] = bias[bn + wn*64 + j*16 + l15];
      // row-completing order: j innermost -> full 128-B line dirty in consecutive stores
      #pragma unroll
      for (int i = 0; i < 8; i++){
        #pragma unroll
        for (int r = 0; r < 4; r++){
          const int t  = tb + i*16 + r;
          const int sw2 = (t & 7) * 8;
          bf16* prow = base + (size_t)t * HD_;
          #pragma unroll
          for (int j = 0; j < 4; j++){
            const int dq = (j*16 + l15) ^ sw2;   // d-swizzle
            short s = f2bs((acc[i][j][r] + bj[j]) * sc);
            prow[dq] = *(bf16*)&s;
          }
        }
      }
    }
  }
}

// ------- GEMM (proj): 128x128 tile, BK=64 two k-sub-stages, counted-vmcnt (round-8) -------
// ROUND 25 (FINAL): VERBATIM round-8 structure; used for gemm1 only.
template<int MODE>
__global__ __launch_bounds__(256, 2) void k_gemm8(
    const bf16* __restrict__ A, const bf16* __restrict__ BT,
    const float* __restrict__ bias,
    bf16* __restrict__ qo, bf16* __restrict__ ko, bf16* __restrict__ vo,
    float* __restrict__ fout,
    int M, int N, int K)
{
  __shared__ bf16 As[2][2][128*32];
  __shared__ bf16 Bs[2][2][128*32];

  const int tid  = threadIdx.x;
  const int wave = tid >> 6, lane = tid & 63;
  const int wm = wave & 1, wn = wave >> 1;          // 2M x 2N wave grid
  const int quad = lane >> 4, l15 = lane & 15;
  const int bm = blockIdx.x * 128;
  const int bn = blockIdx.y * 128;

  const bf16* gA[2]; const bf16* gB[2]; int lofs[2];
  #pragma unroll
  for (int s = 0; s < 2; s++){
    const int c = tid + s*256;
    const int r = c >> 2, p = (c & 3) ^ ((r >> 1) & 3);
    gA[s] = A  + (size_t)(bm + r)*K + p*8;
    gB[s] = BT + (size_t)(bn + r)*K + p*8;
    lofs[s] = c*8;
  }
  const int fsw = (l15 >> 1) & 3;      // fragment-read chunk XOR

  f32x4 acc[4][4] = {};
  const int nT = K >> 6;

  #pragma unroll
  for (int kh = 0; kh < 2; kh++)
    #pragma unroll
    for (int s = 0; s < 2; s++){
      async_load16(gA[s] + kh*32, &As[0][kh][0] + lofs[s]);
      async_load16(gB[s] + kh*32, &Bs[0][kh][0] + lofs[s]);
    }

  for (int u = 0; u < nT; u++){
    const int d = u & 1;
    #pragma unroll
    for (int kh = 0; kh < 2; kh++){
      if (u + 1 < nT || kh == 0) asm volatile("s_waitcnt vmcnt(4)" ::: "memory");
      else                       asm volatile("s_waitcnt vmcnt(0)" ::: "memory");
      __builtin_amdgcn_s_barrier();
      __builtin_amdgcn_sched_barrier(0);

      const bf16* as = &As[d][kh][0];
      const bf16* bs = &Bs[d][kh][0];
      bf16x8 af[4], bfv[4];
      #pragma unroll
      for (int i = 0; i < 4; i++)
        af[i]  = *reinterpret_cast<const bf16x8*>(as + (wm*64 + i*16 + l15)*32 + ((quad ^ fsw) << 3));
      #pragma unroll
      for (int j = 0; j < 4; j++)
        bfv[j] = *reinterpret_cast<const bf16x8*>(bs + (wn*64 + j*16 + l15)*32 + ((quad ^ fsw) << 3));

      if (u + 1 < nT){
        const int ko2 = (u + 1)*64 + kh*32;
        #pragma unroll
        for (int s = 0; s < 2; s++){
          async_load16(gA[s] + ko2, &As[d^1][kh][0] + lofs[s]);
          async_load16(gB[s] + ko2, &Bs[d^1][kh][0] + lofs[s]);
        }
      }

      __builtin_amdgcn_s_setprio(1);
      #pragma unroll
      for (int i = 0; i < 4; i++)
        #pragma unroll
        for (int j = 0; j < 4; j++)
          acc[i][j] = __builtin_amdgcn_mfma_f32_16x16x32_bf16(af[i], bfv[j], acc[i][j], 0, 0, 0);
      __builtin_amdgcn_s_setprio(0);
    }
  }

  if (MODE == 0){
    const int sec = bn >> 10;
    const int bb2 = bm >> 11;
    const int tb  = (bm & (T_ - 1)) + wm*64 + quad*4;
    const int hn  = ((bn & 1023) >> 6) + wn;
    const size_t bhx = (size_t)(bb2 * NH_ + hn);
    if (sec == 2){
      #pragma unroll
      for (int j = 0; j < 4; j++){
        const int d2 = j*16 + l15;
        const float bj = bias[bn + wn*64 + j*16 + l15];
        bf16* vrow = vo + (bhx * HD_ + d2) * (size_t)T_;
        const int sw = (l15 & 7) * 8;
        #pragma unroll
        for (int i = 0; i < 4; i++){
          const int t = (tb + i*16) ^ sw;
          *reinterpret_cast<bf16x4*>(vrow + t) =
            pack_bf16x4(acc[i][j][0] + bj, acc[i][j][1] + bj,
                        acc[i][j][2] + bj, acc[i][j][3] + bj);
        }
      }
    } else {
      bf16* dst = (sec == 0) ? qo : ko;
      const float sc = (sec == 0) ? QSCALE : 1.0f;
      bf16* base = dst + bhx * T_ * HD_;
      float bj[4];
      #pragma unroll
      for (int j = 0; j < 4; j++) bj[j] = bias[bn + wn*64 + j*16 + l15];
      #pragma unroll
      for (int i = 0; i < 4; i++){
        #pragma unroll
        for (int r = 0; r < 4; r++){
          const int t  = tb + i*16 + r;
          const int sw2 = (t & 7) * 8;
          bf16* prow = base + (size_t)t * HD_;
          #pragma unroll
          for (int j = 0; j < 4; j++){
            const int dq = (j*16 + l15) ^ sw2;
            short s = f2bs((acc[i][j][r] + bj[j]) * sc);
            prow[dq] = *(bf16*)&s;
          }
        }
      }
    }
  } else {
    const int n0 = bn + wn*64 + l15;
    float bj[4];
    #pragma unroll
    for (int j = 0; j < 4; j++) bj[j] = bias[n0 + j*16];
    #pragma unroll
    for (int i = 0; i < 4; i++){
      #pragma unroll
      for (int r = 0; r < 4; r++){
        float* p0 = fout + (size_t)(bm + wm*64 + i*16 + quad*4 + r) * N + n0;
        #pragma unroll
        for (int j = 0; j < 4; j++)
          p0[j*16] = acc[i][j][r] + bj[j];
      }
    }
  }
}

// ---------------- flash attention: async dbuf K/V, Q in regs, 128-row q-tiles ----------------
// ROUND 25 (FINAL): round-12 version (verified best; fexp2 + last-tile peel).
__global__ __launch_bounds__(256) void k_attn(
    const bf16* __restrict__ Q, const bf16* __restrict__ Kg,
    const bf16* __restrict__ Vt, bf16* __restrict__ Y)
{
  __shared__ bf16 Ks[2][64*64];   // [kv][d'] unpadded
  __shared__ bf16 Vs[2][64*64];   // [d][kv'] unpadded

  const int bh = blockIdx.x;
  const int bb = bh >> 4, hh = bh & 15;
  const int qt = 15 - blockIdx.y;          // 128-row q-tile, reversed dispatch
  const int tid  = threadIdx.x;
  const int wave = tid >> 6, lane = tid & 63;
  const int quad = lane >> 4, l15 = lane & 15;
  const int swz  = (l15 & 7) * 8;        // fragment-read XOR (t&7 == l15&7 everywhere used)

  const size_t baseQK = (size_t)bh * T_ * HD_;
  const size_t baseV  = (size_t)bh * HD_ * T_;

  const int ca = wave, cb = wave + 4;
  const bf16* kg_a = Kg + baseQK + ca*512 + (size_t)lane*8;
  const bf16* kg_b = Kg + baseQK + cb*512 + (size_t)lane*8;
  const bf16* vg_a = Vt + baseV + (size_t)(ca*8 + (lane>>3)) * T_ + (lane&7)*8;
  const bf16* vg_b = Vt + baseV + (size_t)(cb*8 + (lane>>3)) * T_ + (lane&7)*8;
  bf16* kl_a0 = &Ks[0][0] + ca*512;  bf16* kl_b0 = &Ks[0][0] + cb*512;
  bf16* vl_a0 = &Vs[0][0] + ca*512;  bf16* vl_b0 = &Vs[0][0] + cb*512;

  bf16x4 ones_f;
  {
    short v = (l15 == 0) ? f2bs(1.0f) : (short)0;
    ones_f = (bf16x4){ v, v, v, v };
  }
  const f32x4 ZV = {0.0f, 0.0f, 0.0f, 0.0f};

  bf16x8 qf[2][2];
  #pragma unroll
  for (int s = 0; s < 2; s++){
    const int t = qt*128 + s*64 + wave*16 + l15;
    #pragma unroll
    for (int ks = 0; ks < 2; ks++){
      const int col = (ks*32 + quad*8) ^ swz;
      qf[s][ks] = *reinterpret_cast<const bf16x8*>(Q + baseQK + (size_t)t*HD_ + col);
    }
  }

  async_load16(kg_a, kl_a0);  async_load16(kg_b, kl_b0);
  async_load16(vg_a, vl_a0);  async_load16(vg_b, vl_b0);

  f32x4 o[2][5] = {};

  for (int j = 0; j <= 2*qt; j++){
    __syncthreads();

    {
      const int nb = ((j+1) & 1) * 4096;
      const size_t ko = (size_t)(j+1) * 64 * HD_;
      async_load16(kg_a + ko, kl_a0 + nb);  async_load16(kg_b + ko, kl_b0 + nb);
      async_load16(vg_a + (j+1)*64, vl_a0 + nb);
      async_load16(vg_b + (j+1)*64, vl_b0 + nb);
    }

    const bf16* ksb = &Ks[j & 1][0];
    const bf16* vsb = &Vs[j & 1][0];

    f32x4 st[2][4];
    __builtin_amdgcn_s_setprio(1);
    #pragma unroll
    for (int tk = 0; tk < 4; tk++){
      bf16x8 kf0 = *reinterpret_cast<const bf16x8*>(ksb + (tk*16 + l15)*64 + ((quad*8) ^ swz));
      bf16x8 kf1 = *reinterpret_cast<const bf16x8*>(ksb + (tk*16 + l15)*64 + ((32 + quad*8) ^ swz));
      st[0][tk] = __builtin_amdgcn_mfma_f32_16x16x32_bf16(kf0, qf[0][0], ZV, 0, 0, 0);
      st[1][tk] = __builtin_amdgcn_mfma_f32_16x16x32_bf16(kf0, qf[1][0], ZV, 0, 0, 0);
      st[0][tk] = __builtin_amdgcn_mfma_f32_16x16x32_bf16(kf1, qf[0][1], st[0][tk], 0, 0, 0);
      st[1][tk] = __builtin_amdgcn_mfma_f32_16x16x32_bf16(kf1, qf[1][1], st[1][tk], 0, 0, 0);
    }
    __builtin_amdgcn_s_setprio(0);

    bf16x4 pf[2][4];
    {
      const int qg = qt*128 + wave*16 + l15;
      const bool msk = (j == 2*qt);
      #pragma unroll
      for (int tk = 0; tk < 4; tk++){
        float e[4];
        #pragma unroll
        for (int r = 0; r < 4; r++){
          float sv = st[0][tk][r];
          if (msk){
            const int kvg = j*64 + tk*16 + quad*4 + r;
            if (kvg > qg) sv = -1e30f;
          }
          e[r] = fexp2(sv);
        }
        pf[0][tk] = pack_bf16x4(e[0], e[1], e[2], e[3]);
      }
    }
    #pragma unroll
    for (int tk = 0; tk < 4; tk++){
      float e[4];
      #pragma unroll
      for (int r = 0; r < 4; r++) e[r] = fexp2(st[1][tk][r]);
      pf[1][tk] = pack_bf16x4(e[0], e[1], e[2], e[3]);
    }

    __builtin_amdgcn_s_setprio(1);
    #pragma unroll
    for (int td = 0; td < 4; td++){
      #pragma unroll
      for (int tk = 0; tk < 4; tk++){
        bf16x4 vf = *reinterpret_cast<const bf16x4*>(vsb + (td*16 + l15)*64 + ((tk*16 + quad*4) ^ swz));
        o[0][td] = __builtin_amdgcn_mfma_f32_16x16x16bf16_1k(vf, pf[0][tk], o[0][td], 0, 0, 0);
        o[1][td] = __builtin_amdgcn_mfma_f32_16x16x16bf16_1k(vf, pf[1][tk], o[1][td], 0, 0, 0);
      }
    }
    #pragma unroll
    for (int tk = 0; tk < 4; tk++){
      o[0][4] = __builtin_amdgcn_mfma_f32_16x16x16bf16_1k(ones_f, pf[0][tk], o[0][4], 0, 0, 0);
      o[1][4] = __builtin_amdgcn_mfma_f32_16x16x16bf16_1k(ones_f, pf[1][tk], o[1][4], 0, 0, 0);
    }
    __builtin_amdgcn_s_setprio(0);
  }

  {
    const int j = 2*qt + 1;
    __syncthreads();

    const bf16* ksb = &Ks[j & 1][0];
    const bf16* vsb = &Vs[j & 1][0];

    f32x4 st1[4];
    __builtin_amdgcn_s_setprio(1);
    #pragma unroll
    for (int tk = 0; tk < 4; tk++){
      bf16x8 kf0 = *reinterpret_cast<const bf16x8*>(ksb + (tk*16 + l15)*64 + ((quad*8) ^ swz));
      bf16x8 kf1 = *reinterpret_cast<const bf16x8*>(ksb + (tk*16 + l15)*64 + ((32 + quad*8) ^ swz));
      st1[tk] = __builtin_amdgcn_mfma_f32_16x16x32_bf16(kf0, qf[1][0], ZV, 0, 0, 0);
      st1[tk] = __builtin_amdgcn_mfma_f32_16x16x32_bf16(kf1, qf[1][1], st1[tk], 0, 0, 0);
    }
    __builtin_amdgcn_s_setprio(0);

    bf16x4 pf1[4];
    {
      const int qg = qt*128 + 64 + wave*16 + l15;
      #pragma unroll
      for (int tk = 0; tk < 4; tk++){
        float e[4];
        #pragma unroll
        for (int r = 0; r < 4; r++){
          float sv = st1[tk][r];
          const int kvg = j*64 + tk*16 + quad*4 + r;
          if (kvg > qg) sv = -1e30f;
          e[r] = fexp2(sv);
        }
        pf1[tk] = pack_bf16x4(e[0], e[1], e[2], e[3]);
      }
    }

    __builtin_amdgcn_s_setprio(1);
    #pragma unroll
    for (int td = 0; td < 4; td++){
      #pragma unroll
      for (int tk = 0; tk < 4; tk++){
        bf16x4 vf = *reinterpret_cast<const bf16x4*>(vsb + (td*16 + l15)*64 + ((tk*16 + quad*4) ^ swz));
        o[1][td] = __builtin_amdgcn_mfma_f32_16x16x16bf16_1k(vf, pf1[tk], o[1][td], 0, 0, 0);
      }
    }
    #pragma unroll
    for (int tk = 0; tk < 4; tk++)
      o[1][4] = __builtin_amdgcn_mfma_f32_16x16x16bf16_1k(ones_f, pf1[tk], o[1][4], 0, 0, 0);
    __builtin_amdgcn_s_setprio(0);
  }

  #pragma unroll
  for (int s = 0; s < 2; s++){
    const float l = __shfl(o[s][4][0], l15, 64);
    const float inv = 1.0f / l;
    const int t = qt*128 + s*64 + wave*16 + l15;
    bf16* yrow = Y + ((size_t)(bb * T_ + t)) * C_ + hh * HD_;
    #pragma unroll
    for (int td = 0; td < 4; td++){
      *reinterpret_cast<bf16x4*>(yrow + td*16 + quad*4) =
        pack_bf16x4(o[s][td][0] * inv, o[s][td][1] * inv,
                    o[s][td][2] * inv, o[s][td][3] * inv);
    }
  }
}

// ---------------- launcher ----------------

extern "C" void kernel_launch(void* const* d_in, const int* in_sizes, int n_in,
                              void* d_out, int out_size, void* d_ws, size_t ws_size,
                              hipStream_t stream) {
  const float* x     = (const float*)d_in[0];
  const float* Wqkv  = (const float*)d_in[1];
  const float* bqkv  = (const float*)d_in[2];
  const float* Wproj = (const float*)d_in[3];
  const float* bproj = (const float*)d_in[4];
  float* out = (float*)d_out;

  const size_t M = (size_t)B_ * T_;
  char* w = (char*)d_ws;
  bf16* xb     = (bf16*)w;  w += M * C_ * 2;
  bf16* WqkvT  = (bf16*)w;  w += (size_t)3 * C_ * C_ * 2;
  bf16* WprojT = (bf16*)w;  w += (size_t)C_ * C_ * 2;
  bf16* Qb     = (bf16*)w;  w += M * C_ * 2;
  bf16* Kb     = (bf16*)w;  w += M * C_ * 2;
  bf16* Vtb    = (bf16*)w;  w += M * C_ * 2;
  bf16* Yb     = (bf16*)w;  w += M * C_ * 2;

  // one-time opt-in for 128 KB dynamic LDS on k_gemm256 (host-side, not a stream op)
  static bool attr_done = false;
  if (!attr_done){
    hipFuncSetAttribute(reinterpret_cast<const void*>(k_gemm256),
                        hipFuncAttributeMaxDynamicSharedMemorySize, 131072);
    attr_done = true;
  }

  {
    int n = (int)(M * C_);
    k_prep<<<dim3(12288), dim3(256), 0, stream>>>(x, xb, n, Wqkv, WqkvT, Wproj, WprojT);
  }
  k_gemm256<<<dim3(M/256, (3*C_)/256), dim3(512), 131072, stream>>>(
      xb, WqkvT, bqkv, Qb, Kb, Vtb, (int)M, 3*C_, C_);
  k_attn<<<dim3(64, 16), dim3(256), 0, stream>>>(Qb, Kb, Vtb, Yb);
  k_gemm8<1><<<dim3(M/128, C_/128), dim3(256), 0, stream>>>(
      Yb, WprojT, bproj, nullptr, nullptr, nullptr, out, (int)M, C_, C_);
}